// Round 5
// baseline (785.445 us; speedup 1.0000x reference)
//
#include <hip/hip_runtime.h>
#include <hip/hip_bf16.h>

// Sinkhorn on MI355X. B=64, L=1024, D=256.
// prep (norms + minmax init + zero p-bufs) -> gemm (K=exp(cos-1) fp16; epilogue
//   atomically accumulates p0 = K^T 1 into R0 as fixed-point uint)
//   -> 10x fused F: v=w2/(p/S+eps); z=Kv; u=w1/(z+eps); atomicAdd p'=K^T u
//      (3-buffer rotation: read R[(k-1)%3], add R[k%3], zero R[(k+1)%3])
//   -> fin (out = minmax-norm(u*K*v^T) * (-log K))
// Fixed-point uint atomics: associative-exact -> deterministic.
// WS_NEED = 135528960 <= proven-available 136053248.

#define EPSV 1e-12f
#define W1 0.0009765625f        // 1/1024
#define FIXS 524288.0f          // 2^19
#define INV_FIXS 1.9073486328125e-6f

typedef short  short8 __attribute__((ext_vector_type(8)));
typedef float  f32x4  __attribute__((ext_vector_type(4)));
typedef _Float16 h8   __attribute__((ext_vector_type(8)));

// load 8 consecutive floats, convert to 8 bf16 (hw v_cvt_pk_bf16_f32)
__device__ __forceinline__ short8 ld_cvt8(const float* p) {
  float4 f0 = *(const float4*)p;
  float4 f1 = *(const float4*)(p + 4);
  float2 p0; p0.x = f0.x; p0.y = f0.y;
  float2 p1; p1.x = f0.z; p1.y = f0.w;
  float2 p2; p2.x = f1.x; p2.y = f1.y;
  float2 p3; p3.x = f1.z; p3.y = f1.w;
  __hip_bfloat162 h0 = __float22bfloat162_rn(p0);
  __hip_bfloat162 h1 = __float22bfloat162_rn(p1);
  __hip_bfloat162 h2_ = __float22bfloat162_rn(p2);
  __hip_bfloat162 h3 = __float22bfloat162_rn(p3);
  short2 a = *(short2*)&h0, b = *(short2*)&h1, c = *(short2*)&h2_, d = *(short2*)&h3;
  short8 r;
  r[0] = a.x; r[1] = a.y; r[2] = b.x; r[3] = b.y;
  r[4] = c.x; r[5] = c.y; r[6] = d.x; r[7] = d.y;
  return r;
}

// ---------------------------------------------------------------- diag
__global__ __launch_bounds__(256) void diag_kernel(float* __restrict__ out,
                                                   float val, int n) {
  int stride = gridDim.x * 256;
  for (int i = blockIdx.x * 256 + threadIdx.x; i < n; i += stride) out[i] = val;
}

// ---------------------------------------------------------------- prep
// rows 0..65535 -> x1 norms, 65536..131071 -> x2 norms. 1 wave/row.
// Also: minmax slots init; zero R0+R1 (512 KB = 131072 uints).
__global__ __launch_bounds__(256) void prep_kernel(
    const float* __restrict__ x1, const float* __restrict__ x2,
    float* __restrict__ n1, float* __restrict__ n2,
    unsigned* __restrict__ mm, unsigned* __restrict__ rz) {
  int t = threadIdx.x, bid = blockIdx.x;
  if (bid == 0 && t < 128) mm[t] = (t < 64) ? 0u : 0x7f800000u;
  if (bid < 512) rz[bid * 256 + t] = 0u;
  int row = bid * 4 + (t >> 6);
  int lane = t & 63;
  const float* xp; float* np_;
  int r = row;
  if (row < 65536) { xp = x1; np_ = n1; }
  else { r = row - 65536; xp = x2; np_ = n2; }
  float4 v = ((const float4*)(xp + (size_t)r * 256))[lane];
  float s = v.x * v.x + v.y * v.y + v.z * v.z + v.w * v.w;
  #pragma unroll
  for (int off = 1; off < 64; off <<= 1) s += __shfl_xor(s, off, 64);
  if (lane == 0) np_[r] = sqrtf(s);
}

// ---------------------------------------------------------------- gemm
// 128x128 tile, BK=64, 4 waves (2x2 of 64x64), mfma_f32_16x16x32_bf16.
// Epilogue: K tile -> fp16 store + column sums -> fixed-point atomicAdd to p0.
__global__ __launch_bounds__(256) void gemm_kernel(
    const float* __restrict__ x1, const float* __restrict__ x2,
    const float* __restrict__ n1, const float* __restrict__ n2,
    _Float16* __restrict__ Kh, unsigned* __restrict__ p0) {
  __shared__ __align__(16) unsigned short smem[2 * 128 * 64];  // 32 KB
  __shared__ float csum[4][128];
  unsigned short* As = smem;
  unsigned short* Bs = smem + 128 * 64;
  int bid = blockIdx.x;
  int b = bid >> 6, tile = bid & 63;
  int ti = (tile >> 3) << 7, tj = (tile & 7) << 7;
  int t = threadIdx.x, lane = t & 63, wave = t >> 6;
  int wr = (wave >> 1) << 6, wc = (wave & 1) << 6;
  const float* Ag = x1 + ((size_t)(b * 1024 + ti)) * 256;
  const float* Bg = x2 + ((size_t)(b * 1024 + tj)) * 256;

  f32x4 acc[4][4];
  f32x4 zero = {0.f, 0.f, 0.f, 0.f};
  #pragma unroll
  for (int m = 0; m < 4; ++m)
    #pragma unroll
    for (int n = 0; n < 4; ++n) acc[m][n] = zero;

  short8 ra[4], rb[4];
  #pragma unroll
  for (int c = 0; c < 4; ++c) {
    int ch = t + (c << 8); int row = ch >> 3, kg = ch & 7;
    ra[c] = ld_cvt8(Ag + row * 256 + kg * 8);
    rb[c] = ld_cvt8(Bg + row * 256 + kg * 8);
  }

  for (int k0 = 0; k0 < 4; ++k0) {
    __syncthreads();
    #pragma unroll
    for (int c = 0; c < 4; ++c) {
      int ch = t + (c << 8); int row = ch >> 3, kg = ch & 7;
      int kgs = kg ^ (row & 7);
      *(short8*)(As + row * 64 + kgs * 8) = ra[c];
      *(short8*)(Bs + row * 64 + kgs * 8) = rb[c];
    }
    __syncthreads();
    if (k0 < 3) {
      #pragma unroll
      for (int c = 0; c < 4; ++c) {
        int ch = t + (c << 8); int row = ch >> 3, kg = ch & 7;
        ra[c] = ld_cvt8(Ag + row * 256 + (k0 + 1) * 64 + kg * 8);
        rb[c] = ld_cvt8(Bg + row * 256 + (k0 + 1) * 64 + kg * 8);
      }
    }
    #pragma unroll
    for (int ks = 0; ks < 2; ++ks) {
      short8 af[4], bfr[4];
      #pragma unroll
      for (int m = 0; m < 4; ++m) {
        int row = wr + m * 16 + (lane & 15);
        int c16 = (ks << 2) + (lane >> 4);
        af[m] = *(const short8*)(As + row * 64 + ((c16 ^ (row & 7)) << 3));
      }
      #pragma unroll
      for (int n = 0; n < 4; ++n) {
        int row = wc + n * 16 + (lane & 15);
        int c16 = (ks << 2) + (lane >> 4);
        bfr[n] = *(const short8*)(Bs + row * 64 + ((c16 ^ (row & 7)) << 3));
      }
      #pragma unroll
      for (int m = 0; m < 4; ++m)
        #pragma unroll
        for (int n = 0; n < 4; ++n)
          acc[m][n] = __builtin_amdgcn_mfma_f32_16x16x32_bf16(af[m], bfr[n], acc[m][n], 0, 0, 0);
    }
  }
  __syncthreads();

  // epilogue: cos -> K=exp(cos-1) fp16, repack via LDS for coalesced stores
  _Float16* Ct = (_Float16*)smem;  // 128*128 halves = 32 KB
  float a1v[4][4], b2v[4];
  #pragma unroll
  for (int m = 0; m < 4; ++m)
    #pragma unroll
    for (int q = 0; q < 4; ++q)
      a1v[m][q] = n1[(size_t)b * 1024 + ti + wr + m * 16 + ((lane >> 4) << 2) + q];
  #pragma unroll
  for (int n = 0; n < 4; ++n)
    b2v[n] = n2[(size_t)b * 1024 + tj + wc + n * 16 + (lane & 15)];
  #pragma unroll
  for (int m = 0; m < 4; ++m)
    #pragma unroll
    for (int n = 0; n < 4; ++n)
      #pragma unroll
      for (int q = 0; q < 4; ++q) {
        int rl = wr + m * 16 + ((lane >> 4) << 2) + q;
        int cl = wc + n * 16 + (lane & 15);
        float cosv = acc[m][n][q] / (a1v[m][q] * b2v[n] + EPSV);
        Ct[rl * 128 + cl] = (_Float16)__expf(cosv - 1.0f);
      }
  __syncthreads();
  size_t kbase = ((size_t)b << 20);
  #pragma unroll
  for (int c2i = 0; c2i < 8; ++c2i) {
    int c2 = t + (c2i << 8);
    int row = c2 >> 4, seg = c2 & 15;
    *(float4*)(Kh + kbase + (size_t)(ti + row) * 1024 + tj + seg * 8) = ((const float4*)Ct)[c2];
  }
  // column sums of this 128x128 tile -> fixed-point atomic add
  {
    int cg = lane & 15, rsub = lane >> 4;
    float cs[8];
    #pragma unroll
    for (int k = 0; k < 8; ++k) cs[k] = 0.f;
    #pragma unroll
    for (int i = 0; i < 8; ++i) {
      h8 rowv = *(const h8*)&Ct[(wave * 32 + rsub + i * 4) * 128 + cg * 8];
      #pragma unroll
      for (int k = 0; k < 8; ++k) cs[k] += (float)rowv[k];
    }
    #pragma unroll
    for (int k = 0; k < 8; ++k) {
      cs[k] += __shfl_xor(cs[k], 16, 64);
      cs[k] += __shfl_xor(cs[k], 32, 64);
    }
    if (rsub == 0) {
      #pragma unroll
      for (int k = 0; k < 8; ++k) csum[wave][cg * 8 + k] = cs[k];
    }
    __syncthreads();
    if (t < 128) {
      float s_ = csum[0][t] + csum[1][t] + csum[2][t] + csum[3][t];
      atomicAdd(&p0[((size_t)b << 10) + tj + t], __float2uint_rn(s_ * FIXS));
    }
  }
}

// ---------------------------------------------------------------- fused F
// block = (b, strip s of 64 rows); 8 waves, 1 row per wave-iter, batch 4.
// v = W1/(in/S + eps); z = K v; u = W1/(z+eps); atomicAdd out += K^T u (uint).
// Also zeroes zbuf (next pass's out). FINAL: z rows -> zb, G minmax -> mm.
template<int FINAL>
__global__ __launch_bounds__(512, 4) void fused_kernel(
    const _Float16* __restrict__ Kh, const unsigned* __restrict__ inp,
    unsigned* __restrict__ outp, unsigned* __restrict__ zbuf,
    float* __restrict__ zb, unsigned* __restrict__ mm) {
  int bid = blockIdx.x;
  int b = bid >> 4, s = bid & 15;
  int t = threadIdx.x, lane = t & 63, w = t >> 6;
  __shared__ float sv[1024];
  __shared__ float plds[8][1024];  // 32 KB
  __shared__ float red[16];
  {
    int col2 = t << 1;
    uint2 yv = *(const uint2*)(inp + ((size_t)b << 10) + col2);
    sv[col2]     = W1 / ((float)yv.x * INV_FIXS + EPSV);
    sv[col2 + 1] = W1 / ((float)yv.y * INV_FIXS + EPSV);
  }
  __syncthreads();
  if (!FINAL && t < 64) zbuf[((size_t)b << 10) + (s << 6) + t] = 0u;  // dead buffer this pass
  float svr[16];
  {
    float4 s0 = *(const float4*)&sv[lane * 8];
    float4 s1 = *(const float4*)&sv[lane * 8 + 4];
    float4 s2 = *(const float4*)&sv[512 + lane * 8];
    float4 s3 = *(const float4*)&sv[512 + lane * 8 + 4];
    svr[0] = s0.x;  svr[1] = s0.y;  svr[2]  = s0.z;  svr[3]  = s0.w;
    svr[4] = s1.x;  svr[5] = s1.y;  svr[6]  = s1.z;  svr[7]  = s1.w;
    svr[8] = s2.x;  svr[9] = s2.y;  svr[10] = s2.z;  svr[11] = s2.w;
    svr[12] = s3.x; svr[13] = s3.y; svr[14] = s3.z;  svr[15] = s3.w;
  }
  float pacc[16];
  #pragma unroll
  for (int k = 0; k < 16; ++k) pacc[k] = 0.f;
  float gmn = 3.4e38f, gmx = 0.f;
  const _Float16* kp = Kh + ((size_t)b << 20) + (size_t)(s * 64 + w) * 1024 + lane * 8;
  #pragma unroll
  for (int half = 0; half < 2; ++half) {
    // batch 4 rows: loads together, dots together, butterflies interleaved
    h8 ka[4], kb[4];
    #pragma unroll
    for (int j = 0; j < 4; ++j) {
      int it = half * 4 + j;
      ka[j] = *(const h8*)(kp + (size_t)it * 8192);
      kb[j] = *(const h8*)(kp + (size_t)it * 8192 + 512);
    }
    float dot[4];
    #pragma unroll
    for (int j = 0; j < 4; ++j) {
      float d = 0.f;
      #pragma unroll
      for (int k = 0; k < 8; ++k)
        d += (float)ka[j][k] * svr[k] + (float)kb[j][k] * svr[8 + k];
      dot[j] = d;
    }
    #pragma unroll
    for (int off = 1; off < 64; off <<= 1) {
      #pragma unroll
      for (int j = 0; j < 4; ++j) dot[j] += __shfl_xor(dot[j], off, 64);
    }
    #pragma unroll
    for (int j = 0; j < 4; ++j) {
      int it = half * 4 + j;
      float u = W1 / (dot[j] + EPSV);
      if (FINAL) {
        if (lane == 0) zb[(b << 10) + s * 64 + w + it * 8] = dot[j];
        #pragma unroll
        for (int k = 0; k < 8; ++k) {
          float g0 = u * (float)ka[j][k] * svr[k];
          float g1 = u * (float)kb[j][k] * svr[8 + k];
          gmn = fminf(gmn, fminf(g0, g1)); gmx = fmaxf(gmx, fmaxf(g0, g1));
        }
      } else {
        #pragma unroll
        for (int k = 0; k < 8; ++k) {
          pacc[k] += (float)ka[j][k] * u;
          pacc[8 + k] += (float)kb[j][k] * u;
        }
      }
    }
  }
  if (!FINAL) {
    float4 v0 = {pacc[0], pacc[1], pacc[2], pacc[3]};
    float4 v1 = {pacc[4], pacc[5], pacc[6], pacc[7]};
    float4 v2 = {pacc[8], pacc[9], pacc[10], pacc[11]};
    float4 v3 = {pacc[12], pacc[13], pacc[14], pacc[15]};
    *(float4*)&plds[w][lane * 8] = v0;
    *(float4*)&plds[w][lane * 8 + 4] = v1;
    *(float4*)&plds[w][512 + lane * 8] = v2;
    *(float4*)&plds[w][512 + lane * 8 + 4] = v3;
    __syncthreads();
    #pragma unroll
    for (int p = 0; p < 2; ++p) {
      int col = (p << 9) + t;
      float sum = plds[0][col] + plds[1][col] + plds[2][col] + plds[3][col]
                + plds[4][col] + plds[5][col] + plds[6][col] + plds[7][col];
      atomicAdd(&outp[((size_t)b << 10) + col], __float2uint_rn(sum * FIXS));
    }
  } else {
    #pragma unroll
    for (int off = 1; off < 64; off <<= 1) {
      gmn = fminf(gmn, __shfl_xor(gmn, off, 64));
      gmx = fmaxf(gmx, __shfl_xor(gmx, off, 64));
    }
    if (lane == 0) { red[w] = gmn; red[8 + w] = gmx; }
    __syncthreads();
    if (t == 0) {
      float m0 = red[0], m1 = red[8];
      #pragma unroll
      for (int i = 1; i < 8; ++i) { m0 = fminf(m0, red[i]); m1 = fmaxf(m1, red[8 + i]); }
      atomicMin(&mm[64 + b], __float_as_uint(m0));  // positive floats: uint order ok
      atomicMax(&mm[b],      __float_as_uint(m1));
    }
  }
}

// ---------------------------------------------------------------- fin
// out = ((G - gmin) / (gmax - gmin + eps)) * (-log K); v from uint partials.
__global__ __launch_bounds__(256) void fin_kernel(
    const _Float16* __restrict__ Kh, const unsigned* __restrict__ src,
    const float* __restrict__ zb, const unsigned* __restrict__ mm,
    float* __restrict__ out) {
  int bid = blockIdx.x;
  int b = bid >> 4, rg = bid & 15;
  int t = threadIdx.x, lane = t & 63, w = t >> 6;
  __shared__ float sv[1024];
  #pragma unroll
  for (int p = 0; p < 2; ++p) {
    int col2 = (p << 9) + (t << 1);
    uint2 yv = *(const uint2*)(src + ((size_t)b << 10) + col2);
    sv[col2]     = W1 / ((float)yv.x * INV_FIXS + EPSV);
    sv[col2 + 1] = W1 / ((float)yv.y * INV_FIXS + EPSV);
  }
  __syncthreads();
  float svr[16];
  {
    float4 s0 = *(const float4*)&sv[lane * 8];
    float4 s1 = *(const float4*)&sv[lane * 8 + 4];
    float4 s2 = *(const float4*)&sv[512 + lane * 8];
    float4 s3 = *(const float4*)&sv[512 + lane * 8 + 4];
    svr[0] = s0.x;  svr[1] = s0.y;  svr[2]  = s0.z;  svr[3]  = s0.w;
    svr[4] = s1.x;  svr[5] = s1.y;  svr[6]  = s1.z;  svr[7]  = s1.w;
    svr[8] = s2.x;  svr[9] = s2.y;  svr[10] = s2.z;  svr[11] = s2.w;
    svr[12] = s3.x; svr[13] = s3.y; svr[14] = s3.z;  svr[15] = s3.w;
  }
  float gmx = __uint_as_float(mm[b]);
  float gmn = __uint_as_float(mm[64 + b]);
  float scale = 1.0f / (gmx - gmn + EPSV);
  const _Float16* kp = Kh + ((size_t)b << 20) + (size_t)(rg * 64 + w) * 1024 + lane * 8;
  float* op = out + ((size_t)b << 20) + (size_t)(rg * 64 + w) * 1024 + lane * 8;
  for (int it = 0; it < 16; ++it) {
    int r = rg * 64 + w + it * 4;
    float u = W1 / (zb[b * 1024 + r] + EPSV);
    h8 k0 = *(const h8*)(kp + (size_t)it * 4096);
    h8 k1 = *(const h8*)(kp + (size_t)it * 4096 + 512);
    float o[16];
    #pragma unroll
    for (int k = 0; k < 8; ++k) {
      float kfa = (float)k0[k];
      float kfb = (float)k1[k];
      float ga = u * kfa * svr[k];
      float gb = u * kfb * svr[8 + k];
      o[k]     = (ga - gmn) * scale * (-__logf(kfa));
      o[8 + k] = (gb - gmn) * scale * (-__logf(kfb));
    }
    float4 o0 = {o[0], o[1], o[2], o[3]};
    float4 o1 = {o[4], o[5], o[6], o[7]};
    float4 o2 = {o[8], o[9], o[10], o[11]};
    float4 o3 = {o[12], o[13], o[14], o[15]};
    *(float4*)(op + (size_t)it * 4096) = o0;
    *(float4*)(op + (size_t)it * 4096 + 4) = o1;
    *(float4*)(op + (size_t)it * 4096 + 512) = o2;
    *(float4*)(op + (size_t)it * 4096 + 516) = o3;
  }
}

// ---------------------------------------------------------------- launch
extern "C" void kernel_launch(void* const* d_in, const int* in_sizes, int n_in,
                              void* d_out, int out_size, void* d_ws, size_t ws_size,
                              hipStream_t stream) {
  const float* x1 = (const float*)d_in[0];
  const float* x2 = (const float*)d_in[1];
  float* out = (float*)d_out;
  char* ws = (char*)d_ws;

  // ws layout (bytes)
  _Float16* Kh = (_Float16*)(ws);                 // 134217728
  float*    n1 = (float*)(ws + 134217728ULL);     // 262144 (reused as zb after gemm)
  float*    zb = (float*)(ws + 134217728ULL);
  float*    n2 = (float*)(ws + 134479872ULL);     // 262144
  unsigned* R0 = (unsigned*)(ws + 134742016ULL);  // 262144
  unsigned* R1 = (unsigned*)(ws + 135004160ULL);  // 262144
  unsigned* R2 = (unsigned*)(ws + 135266304ULL);  // 262144
  unsigned* mm = (unsigned*)(ws + 135528448ULL);  // 512
  const size_t WS_NEED = 135528960ULL;            // <= proven-available 136053248
  unsigned* R[3] = {R0, R1, R2};

  if (ws_size < WS_NEED) {
    float val = 100.0f + (float)(ws_size >> 20);
    diag_kernel<<<2048, 256, 0, stream>>>(out, val, out_size);
    return;
  }

  prep_kernel<<<32768, 256, 0, stream>>>(x1, x2, n1, n2, mm, R0);
  gemm_kernel<<<4096, 256, 0, stream>>>(x1, x2, n1, n2, Kh, R0);
  // rotation: pass k reads R[(k-1)%3], adds into R[k%3] (pre-zeroed),
  // zeroes R[(k+1)%3] for pass k+1. prep zeroed R0,R1; pass1 zeroes R2; etc.
  for (int k = 1; k <= 9; ++k)
    fused_kernel<0><<<1024, 512, 0, stream>>>(Kh, R[(k - 1) % 3], R[k % 3],
                                              R[(k + 1) % 3], zb, mm);
  // k=10 FINAL: reads R0 (=p9), writes zb + minmax only
  fused_kernel<1><<<1024, 512, 0, stream>>>(Kh, R0, R1, R2, zb, mm);
  fin_kernel<<<1024, 256, 0, stream>>>(Kh, R0, zb, mm, out);
}